// Round 1
// baseline (611.577 us; speedup 1.0000x reference)
//
#include <hip/hip_runtime.h>
#include <stdint.h>

#define PHM      4
#define IN_FEATS 2048
#define OUT_FEATS 8192
#define TOKENS   8192
#define IN_PER   512    // IN_FEATS / PHM
#define OUT_PER  2048   // OUT_FEATS / PHM

typedef __attribute__((ext_vector_type(8)))  short short8;
typedef __attribute__((ext_vector_type(16))) float f32x16;
typedef __attribute__((ext_vector_type(8)))  unsigned short u16x8;

// round-to-nearest-even fp32 -> bf16 (inputs are finite Gaussians, no NaN path)
__device__ inline unsigned short f2bf(float f) {
    unsigned int u = __builtin_bit_cast(unsigned int, f);
    u += 0x7fffu + ((u >> 16) & 1u);
    return (unsigned short)(u >> 16);
}

// ---------------- kernel 1: x fp32 -> bf16, 8 elem/thread ----------------
__global__ void cvt_x_kernel(const float* __restrict__ x,
                             unsigned short* __restrict__ xb) {
    int i = blockIdx.x * blockDim.x + threadIdx.x;  // one per 8 elements
    const float4* x4 = (const float4*)x;
    float4 v0 = x4[2 * i];
    float4 v1 = x4[2 * i + 1];
    u16x8 o;
    o[0] = f2bf(v0.x); o[1] = f2bf(v0.y); o[2] = f2bf(v0.z); o[3] = f2bf(v0.w);
    o[4] = f2bf(v1.x); o[5] = f2bf(v1.y); o[6] = f2bf(v1.z); o[7] = f2bf(v1.w);
    *(u16x8*)(xb + 8 * (size_t)i) = o;
}

// ---------------- kernel 2: build Ht[n][k] = sum_i rule[i,a,kq]*W[i,c,p] ----
__global__ void build_ht_kernel(const float* __restrict__ rule,  // [4][4][4] (i,a,kq)
                                const float* __restrict__ W,     // [4][512][2048]
                                unsigned short* __restrict__ Ht) // [8192][2048] bf16
{
    __shared__ float lds[PHM][32][65];  // +1 pad: conflict-free column reads
    const int tid = threadIdx.x;
    const int c0 = blockIdx.x * 32;
    const int p0 = blockIdx.y * 64;

    #pragma unroll
    for (int it = 0; it < 32; ++it) {
        int idx = it * 256 + tid;        // 0..8191
        int pp = idx & 63;
        int cc = (idx >> 6) & 31;
        int i  = idx >> 11;
        lds[i][cc][pp] = W[((size_t)(i * IN_PER + c0 + cc)) * OUT_PER + p0 + pp];
    }
    __syncthreads();

    const int pp = tid >> 2;         // 0..63
    const int j0 = (tid & 3) * 8;    // c-chunk of 8
    float w[PHM][8];
    #pragma unroll
    for (int i = 0; i < PHM; ++i)
        #pragma unroll
        for (int j = 0; j < 8; ++j)
            w[i][j] = lds[i][j0 + j][pp];

    #pragma unroll
    for (int a = 0; a < PHM; ++a) {
        #pragma unroll
        for (int kq = 0; kq < PHM; ++kq) {
            float r0 = rule[(0 * PHM + a) * PHM + kq];
            float r1 = rule[(1 * PHM + a) * PHM + kq];
            float r2 = rule[(2 * PHM + a) * PHM + kq];
            float r3 = rule[(3 * PHM + a) * PHM + kq];
            u16x8 o;
            #pragma unroll
            for (int j = 0; j < 8; ++j) {
                float v = r0 * w[0][j] + r1 * w[1][j] + r2 * w[2][j] + r3 * w[3][j];
                o[j] = f2bf(v);
            }
            size_t n = (size_t)(kq * OUT_PER + p0 + pp);
            *(u16x8*)(Ht + n * IN_FEATS + a * IN_PER + c0 + j0) = o;  // 16B coalesced
        }
    }
}

// ---------------- kernel 3: C[M][N] = A[M][K] * B[N][K]^T + bias ------------
// Round-4: 256x256 tile, 8 waves (2x4), wave tile 128x64 as 4x2 of
// mfma_f32_32x32x16_bf16.  BK=32, TRIPLE-buffered LDS (96 KiB) so tile t+2's
// global_load_lds stay in flight across the t->t+1 boundary: the boundary
// wait is s_waitcnt vmcnt(4) (counted, never 0 until the epilogue) + raw
// s_barrier (no auto-drain).  Two phases per K-tile, each
// {8 ds_read_b128 || 2 global_load_lds -> barrier -> lgkmcnt(0) ->
//  setprio(1) 8 MFMA setprio(0)} -- m201-template cadence.
// T2 LDS swizzle: 16B-chunk ^= (row>>1)&3, realized as linear gload_lds dest
// + inverse-swizzled per-lane GLOBAL source + swizzled ds_read address.
// T1 XCD swizzle on the 1024-block grid (1024 % 8 == 0, bijective).
#define BM 256
#define BN 256
#define BK 32
#define NTILES (IN_FEATS / BK)   // 64
#define LTILE  (BM * BK)         // 8192 ushorts = 16 KiB per operand tile

__device__ inline void gload16(const unsigned short* g, unsigned short* l) {
    __builtin_amdgcn_global_load_lds(
        (const __attribute__((address_space(1))) unsigned int*)g,
        (__attribute__((address_space(3))) unsigned int*)l,
        16, 0, 0);
}

// raw s_barrier with compiler memory fences (no vmcnt/lgkm auto-drain;
// fences stop the compiler moving LDS reads / load-issues across it)
__device__ inline void barrier_fenced() {
    asm volatile("" ::: "memory");
    __builtin_amdgcn_s_barrier();
    asm volatile("" ::: "memory");
}

__global__ __launch_bounds__(512, 2) void gemm_bt_kernel(
    const unsigned short* __restrict__ A,   // [M][K] bf16 (x)
    const unsigned short* __restrict__ B,   // [N][K] bf16 (Ht)
    const float* __restrict__ bias,         // [N]
    float* __restrict__ C)                  // [M][N] fp32
{
    constexpr int N = OUT_FEATS, K = IN_FEATS;
    constexpr int NXB = OUT_FEATS / BN;              // 32 tiles in N
    constexpr int NWG = (TOKENS / BM) * NXB;         // 1024 workgroups

    __shared__ unsigned short As[3 * LTILE];         // 48 KiB
    __shared__ unsigned short Bs[3 * LTILE];         // 48 KiB

    const int tid  = threadIdx.x;
    const int wave = tid >> 6;
    const int lane = tid & 63;
    const int lm   = lane & 31;                      // MFMA row within fragment
    const int kh   = lane >> 5;                      // which 8-k half of k16

    // T1: XCD-aware bijective swizzle (8 XCDs round-robin on linear id)
    const int orig = blockIdx.y * NXB + blockIdx.x;
    const int swzb = (orig & 7) * (NWG >> 3) + (orig >> 3);
    const int bn = swzb & (NXB - 1);
    const int bm = swzb >> 5;

    const int wm = (wave >> 2) * 128;                // wave's 128-row band
    const int wn = (wave & 3) * 64;                  // wave's 64-col band

    // ---- precomputed swizzled LDS read offsets (ushort units) ----
    // chunk(k16) lives at slot k16 ^ ((row>>1)&3) within the 64B row
    int offA[2][2][2];   // [mh][mf][ks]
    int offB[2][2];      // [nf][ks]
    #pragma unroll
    for (int mh = 0; mh < 2; ++mh)
        #pragma unroll
        for (int mf = 0; mf < 2; ++mf)
            #pragma unroll
            for (int ks = 0; ks < 2; ++ks) {
                int r   = wm + (mh * 2 + mf) * 32 + lm;
                int k16 = ks * 2 + kh;
                offA[mh][mf][ks] = r * BK + ((k16 ^ ((r >> 1) & 3)) << 3);
            }
    #pragma unroll
    for (int nf = 0; nf < 2; ++nf)
        #pragma unroll
        for (int ks = 0; ks < 2; ++ks) {
            int r   = wn + nf * 32 + lm;
            int k16 = ks * 2 + kh;
            offB[nf][ks] = r * BK + ((k16 ^ ((r >> 1) & 3)) << 3);
        }

    // ---- staging maps (linear LDS dest, inverse-swizzled global source) ----
    // thread t covers LDS 16B chunk t -> row t>>2, slot t&3; that slot holds
    // global chunk (t&3) ^ ((t>>3)&3)   [(row>>1)&3 == (t>>3)&3]
    const int srow = tid >> 2;                               // 0..127
    const int scol = (((tid & 3) ^ ((tid >> 3) & 3)) << 3);  // ushort col
    const unsigned short* Ag0 = A + (size_t)(bm * BM + srow) * K + scol;
    const unsigned short* Ag1 = Ag0 + (size_t)128 * K;
    const unsigned short* Bg0 = B + (size_t)(bn * BN + srow) * K + scol;
    const unsigned short* Bg1 = Bg0 + (size_t)128 * K;
    unsigned short* const As_d0 = As + wave * 16 * BK;       // wave-uniform dests
    unsigned short* const As_d1 = As_d0 + 128 * BK;
    unsigned short* const Bs_d0 = Bs + wave * 16 * BK;
    unsigned short* const Bs_d1 = Bs_d0 + 128 * BK;

    #define STAGE_A(koff, so) do { \
        gload16(Ag0 + (koff), As_d0 + (so)); \
        gload16(Ag1 + (koff), As_d1 + (so)); } while (0)
    #define STAGE_B(koff, so) do { \
        gload16(Bg0 + (koff), Bs_d0 + (so)); \
        gload16(Bg1 + (koff), Bs_d1 + (so)); } while (0)

    // ---- prologue: tile0 -> buf0, tile1 -> buf1; wait only for tile0 ----
    STAGE_A(0, 0);            STAGE_B(0, 0);
    STAGE_A(BK, LTILE);       STAGE_B(BK, LTILE);
    asm volatile("s_waitcnt vmcnt(4)" ::: "memory");   // tile0 resident
    barrier_fenced();

    f32x16 acc[4][2] = {};   // [m-frag 0..3][n-frag 0..1]
    int cur = 0, stg = 2;

    #pragma unroll 1
    for (int t = 0; t < NTILES; ++t) {
        const unsigned short* Ab = As + cur * LTILE;
        const unsigned short* Bb = Bs + cur * LTILE;
        const bool st   = (t + 2) < NTILES;
        const int  k2   = (t + 2) * BK;
        const int  so   = stg * LTILE;

        short8 a[2][2], b[2][2];

        // ======== phase 1: read A(mh=0) + all B ; stage A(t+2) ========
        #pragma unroll
        for (int mf = 0; mf < 2; ++mf)
            #pragma unroll
            for (int ks = 0; ks < 2; ++ks)
                a[mf][ks] = *(const short8*)(Ab + offA[0][mf][ks]);
        #pragma unroll
        for (int nf = 0; nf < 2; ++nf)
            #pragma unroll
            for (int ks = 0; ks < 2; ++ks)
                b[nf][ks] = *(const short8*)(Bb + offB[nf][ks]);
        if (st) STAGE_A(k2, so);
        barrier_fenced();
        asm volatile("s_waitcnt lgkmcnt(0)" ::: "memory");
        __builtin_amdgcn_sched_barrier(0);
        __builtin_amdgcn_s_setprio(1);
        #pragma unroll
        for (int ks = 0; ks < 2; ++ks)
            #pragma unroll
            for (int mf = 0; mf < 2; ++mf)
                #pragma unroll
                for (int nf = 0; nf < 2; ++nf)
                    acc[mf][nf] = __builtin_amdgcn_mfma_f32_32x32x16_bf16(
                        a[mf][ks], b[nf][ks], acc[mf][nf], 0, 0, 0);
        __builtin_amdgcn_s_setprio(0);
        barrier_fenced();

        // ======== phase 2: read A(mh=1) ; stage B(t+2) ; boundary wait ====
        #pragma unroll
        for (int mf = 0; mf < 2; ++mf)
            #pragma unroll
            for (int ks = 0; ks < 2; ++ks)
                a[mf][ks] = *(const short8*)(Ab + offA[1][mf][ks]);
        if (st) STAGE_B(k2, so);
        barrier_fenced();
        asm volatile("s_waitcnt lgkmcnt(0)" ::: "memory");
        __builtin_amdgcn_sched_barrier(0);
        __builtin_amdgcn_s_setprio(1);
        #pragma unroll
        for (int ks = 0; ks < 2; ++ks)
            #pragma unroll
            for (int mf = 0; mf < 2; ++mf)
                #pragma unroll
                for (int nf = 0; nf < 2; ++nf)
                    acc[2 + mf][nf] = __builtin_amdgcn_mfma_f32_32x32x16_bf16(
                        a[mf][ks], b[nf][ks], acc[2 + mf][nf], 0, 0, 0);
        __builtin_amdgcn_s_setprio(0);
        // counted boundary wait: retire tile t+1's 4 loads, keep tile t+2's
        // 4 in flight across the barrier (T4).  Tail: full drain.
        if (t < NTILES - 2) asm volatile("s_waitcnt vmcnt(4)" ::: "memory");
        else                asm volatile("s_waitcnt vmcnt(0)" ::: "memory");
        barrier_fenced();

        cur = (cur == 2) ? 0 : cur + 1;
        stg = (stg == 2) ? 0 : stg + 1;
    }
    #undef STAGE_A
    #undef STAGE_B

    // epilogue: 32x32 C/D layout col=lane&31, row=(reg&3)+8*(reg>>2)+4*(lane>>5)
    const int cn = lm;
    const int rb = 4 * kh;
    #pragma unroll
    for (int j = 0; j < 2; ++j) {
        const int col = bn * BN + wn + j * 32 + cn;
        const float bv = bias[col];
        #pragma unroll
        for (int i = 0; i < 4; ++i) {
            const int row0 = bm * BM + wm + i * 32 + rb;
            #pragma unroll
            for (int reg = 0; reg < 16; ++reg) {
                int row = row0 + (reg & 3) + 8 * (reg >> 2);
                C[(size_t)row * N + col] = acc[i][j][reg] + bv;
            }
        }
    }
}

extern "C" void kernel_launch(void* const* d_in, const int* in_sizes, int n_in,
                              void* d_out, int out_size, void* d_ws, size_t ws_size,
                              hipStream_t stream) {
    const float* x    = (const float*)d_in[0];   // [8192][2048]
    const float* rule = (const float*)d_in[1];   // [4][4][4]
    const float* W    = (const float*)d_in[2];   // [4][512][2048]
    const float* b    = (const float*)d_in[3];   // [8192]
    float* y = (float*)d_out;                    // [8192][8192]

    unsigned short* xb = (unsigned short*)d_ws;                       // 32 MB
    unsigned short* Ht = (unsigned short*)((char*)d_ws +
                         (size_t)TOKENS * IN_FEATS * sizeof(unsigned short)); // 32 MB

    cvt_x_kernel<<<(TOKENS * IN_FEATS) / 8 / 256, 256, 0, stream>>>(x, xb);
    build_ht_kernel<<<dim3(IN_PER / 32, OUT_PER / 64), 256, 0, stream>>>(rule, W, Ht);
    gemm_bt_kernel<<<dim3(OUT_FEATS / BN, TOKENS / BM), 512, 0, stream>>>(xb, Ht, b, y);
}